// Round 1
// baseline (2193.409 us; speedup 1.0000x reference)
//
#include <hip/hip_runtime.h>
#include <hip/hip_bf16.h>

#define N_FINE 50000
#define N_COARSE 2000
#define N_EDGES 300000
#define HID 512

static inline int cdiv(int a, int b) { return (a + b - 1) / b; }

// ---------------- CSR build ----------------

__global__ void count_edges_kernel(const int* __restrict__ col, int* __restrict__ counts, int ne) {
    int e = blockIdx.x * 256 + threadIdx.x;
    if (e < ne) atomicAdd(&counts[col[e]], 1);
}

__global__ void compute_dis_kernel(const int* __restrict__ counts, float* __restrict__ dis, int n) {
    int i = blockIdx.x * 256 + threadIdx.x;
    if (i < n) dis[i] = rsqrtf((float)(counts[i] + 1));   // +1 self loop
}

// single-block exclusive scan, n up to ~64k
__global__ __launch_bounds__(1024) void scan_kernel(const int* __restrict__ counts, int* __restrict__ rowptr, int n) {
    __shared__ int buf[1024];
    __shared__ int carry_s;
    int tid = threadIdx.x;
    if (tid == 0) carry_s = 0;
    __syncthreads();
    for (int base = 0; base < n; base += 1024) {
        int i = base + tid;
        int v = (i < n) ? counts[i] : 0;
        buf[tid] = v;
        __syncthreads();
        for (int off = 1; off < 1024; off <<= 1) {
            int t = (tid >= off) ? buf[tid - off] : 0;
            __syncthreads();
            buf[tid] += t;
            __syncthreads();
        }
        int incl = buf[tid];
        int carry = carry_s;
        if (i < n) rowptr[i] = carry + incl - v;   // exclusive
        __syncthreads();
        if (tid == 0) carry_s = carry + buf[1023];
        __syncthreads();
    }
    if (tid == 0) rowptr[n] = carry_s;
}

__global__ void scatter_edges_kernel(const int* __restrict__ row, const int* __restrict__ col,
                                     int* __restrict__ cursor, int* __restrict__ esrc, int ne) {
    int e = blockIdx.x * 256 + threadIdx.x;
    if (e < ne) {
        int p = atomicAdd(&cursor[col[e]], 1);
        esrc[p] = row[e];
    }
}

// ---------------- layer kernels ----------------

// first layer GEMM: [M,6] @ [6,512], output scaled by dis (t2 = dis * (h@W))
__global__ void pre0_kernel(const float* __restrict__ x, const float* __restrict__ sdf,
                            const float* __restrict__ W, const float* __restrict__ dis,
                            float* __restrict__ B, int M) {
    int idx = blockIdx.x * 256 + threadIdx.x;
    int m = idx >> 9, n = idx & 511;
    if (m >= M) return;
    float a0 = x[m*5+0], a1 = x[m*5+1], a2 = x[m*5+2], a3 = x[m*5+3], a4 = x[m*5+4], a5 = sdf[m];
    float t = a0*W[n] + a1*W[512+n] + a2*W[1024+n] + a3*W[1536+n] + a4*W[2048+n] + a5*W[2560+n];
    B[m*512+n] = dis[m] * t;
}

// C[M,512] = dis .* (A[M,512] @ W[512,512]  (+ A2[M,3] @ W2[3,512]) )
// tiles: BM=64,BN=64,BK=32; 256 threads, 4x4 per thread
__global__ __launch_bounds__(256) void gemm512_kernel(
        const float* __restrict__ A, const float* __restrict__ W,
        const float* __restrict__ dis, float* __restrict__ C, int M,
        const float* __restrict__ A2, const float* __restrict__ W2) {
    __shared__ float As[64][36];   // [m][k], padded to keep 16B alignment
    __shared__ float Bs[32][64];   // [k][n]
    int tid = threadIdx.x;
    int row0 = blockIdx.x * 64;
    int col0 = blockIdx.y * 64;
    int tx = tid & 15, ty = tid >> 4;
    float acc[4][4] = {{0.f}};
    for (int k0 = 0; k0 < 512; k0 += 32) {
#pragma unroll
        for (int i = 0; i < 2; ++i) {
            int q = i * 256 + tid;
            int m = q >> 3;
            int kq = (q & 7) << 2;
            int gm = row0 + m; if (gm >= M) gm = M - 1;
            float4 av = *reinterpret_cast<const float4*>(&A[(size_t)gm * 512 + k0 + kq]);
            *reinterpret_cast<float4*>(&As[m][kq]) = av;
        }
#pragma unroll
        for (int i = 0; i < 2; ++i) {
            int q = i * 256 + tid;
            int k = q >> 4;
            int n = (q & 15) << 2;
            float4 wv = *reinterpret_cast<const float4*>(&W[(size_t)(k0 + k) * 512 + col0 + n]);
            *reinterpret_cast<float4*>(&Bs[k][n]) = wv;
        }
        __syncthreads();
#pragma unroll
        for (int k = 0; k < 32; k += 4) {
            float4 a[4], b[4];
#pragma unroll
            for (int mi = 0; mi < 4; ++mi) a[mi] = *reinterpret_cast<const float4*>(&As[ty*4+mi][k]);
#pragma unroll
            for (int kk = 0; kk < 4; ++kk) b[kk] = *reinterpret_cast<const float4*>(&Bs[k+kk][tx*4]);
#pragma unroll
            for (int mi = 0; mi < 4; ++mi) {
                const float* ap = reinterpret_cast<const float*>(&a[mi]);
#pragma unroll
                for (int kk = 0; kk < 4; ++kk) {
                    const float* bp = reinterpret_cast<const float*>(&b[kk]);
                    acc[mi][0] += ap[kk] * bp[0];
                    acc[mi][1] += ap[kk] * bp[1];
                    acc[mi][2] += ap[kk] * bp[2];
                    acc[mi][3] += ap[kk] * bp[3];
                }
            }
        }
        __syncthreads();
    }
#pragma unroll
    for (int mi = 0; mi < 4; ++mi) {
        int m = row0 + ty * 4 + mi;
        if (m >= M) continue;
        float d = dis[m];
        float ex[4] = {0.f, 0.f, 0.f, 0.f};
        if (A2) {
            float a20 = A2[m*3+0], a21 = A2[m*3+1], a22 = A2[m*3+2];
#pragma unroll
            for (int ni = 0; ni < 4; ++ni) {
                int n = col0 + tx * 4 + ni;
                ex[ni] = a20 * W2[n] + a21 * W2[512 + n] + a22 * W2[1024 + n];
            }
        }
#pragma unroll
        for (int ni = 0; ni < 4; ++ni) {
            int n = col0 + tx * 4 + ni;
            C[(size_t)m * 512 + n] = d * (acc[mi][ni] + ex[ni]);
        }
    }
}

// out[i,:] = relu( dis[i] * (sum_{nbr} B[src,:] + B[i,:]) + bias )  -- width 512
__global__ __launch_bounds__(256) void spmm512_kernel(
        const float* __restrict__ B, const int* __restrict__ rowptr, const int* __restrict__ esrc,
        const float* __restrict__ dis, const float* __restrict__ bias,
        float* __restrict__ out, int do_relu) {
    int i = blockIdx.x;
    int c = threadIdx.x;
    float acc0 = B[(size_t)i * 512 + c];          // self loop
    float acc1 = B[(size_t)i * 512 + c + 256];
    int s = rowptr[i], e = rowptr[i + 1];
    for (int p = s; p < e; ++p) {
        int src = esrc[p];
        acc0 += B[(size_t)src * 512 + c];
        acc1 += B[(size_t)src * 512 + c + 256];
    }
    float d = dis[i];
    float v0 = d * acc0 + bias[c];
    float v1 = d * acc1 + bias[c + 256];
    if (do_relu) { v0 = fmaxf(v0, 0.f); v1 = fmaxf(v1, 0.f); }
    out[(size_t)i * 512 + c] = v0;
    out[(size_t)i * 512 + c + 256] = v1;
}

// final GEMM: B3[M,3] = dis .* (A[M,512] @ W[512,3]); one wave per row
__global__ __launch_bounds__(256) void gemm_n3_kernel(
        const float* __restrict__ A, const float* __restrict__ W,
        const float* __restrict__ dis, float* __restrict__ B3, int M) {
    int wid = (blockIdx.x * blockDim.x + threadIdx.x) >> 6;
    int lane = threadIdx.x & 63;
    if (wid >= M) return;
    const float* a = A + (size_t)wid * 512;
    float s0 = 0.f, s1 = 0.f, s2 = 0.f;
    for (int k = lane; k < 512; k += 64) {
        float av = a[k];
        s0 += av * W[k*3+0];
        s1 += av * W[k*3+1];
        s2 += av * W[k*3+2];
    }
    for (int off = 32; off > 0; off >>= 1) {
        s0 += __shfl_down(s0, off);
        s1 += __shfl_down(s1, off);
        s2 += __shfl_down(s2, off);
    }
    if (lane == 0) {
        float d = dis[wid];
        B3[wid*3+0] = d * s0;
        B3[wid*3+1] = d * s1;
        B3[wid*3+2] = d * s2;
    }
}

__global__ void spmm3_kernel(const float* __restrict__ B3, const int* __restrict__ rowptr,
                             const int* __restrict__ esrc, const float* __restrict__ dis,
                             const float* __restrict__ bias, float* __restrict__ out, int M) {
    int i = blockIdx.x * 256 + threadIdx.x;
    if (i >= M) return;
    float a0 = B3[i*3+0], a1 = B3[i*3+1], a2 = B3[i*3+2];
    int s = rowptr[i], e = rowptr[i + 1];
    for (int p = s; p < e; ++p) {
        int src = esrc[p];
        a0 += B3[src*3+0];
        a1 += B3[src*3+1];
        a2 += B3[src*3+2];
    }
    float d = dis[i];
    out[i*3+0] = d * a0 + bias[0];
    out[i*3+1] = d * a1 + bias[1];
    out[i*3+2] = d * a2 + bias[2];
}

// KNN interpolate: for each fine node, 3 nearest coarse nodes (ref distance formula)
__global__ __launch_bounds__(256) void knn_kernel(
        const float* __restrict__ x /*[M,5]*/, const float* __restrict__ cpos /*[NC,2]*/,
        const float* __restrict__ cy /*[NC,3]*/, float* __restrict__ fy /*[M,3]*/, int M) {
    __shared__ float scx[N_COARSE];
    __shared__ float scy[N_COARSE];
    __shared__ float sn2[N_COARSE];
    for (int t = threadIdx.x; t < N_COARSE; t += 256) {
        float a = cpos[t*2+0], b = cpos[t*2+1];
        scx[t] = a; scy[t] = b; sn2[t] = a*a + b*b;
    }
    __syncthreads();
    int i = blockIdx.x * 256 + threadIdx.x;
    if (i >= M) return;
    float px = x[i*5+0], py = x[i*5+1];
    float pn2 = px*px + py*py;
    float d0 = 3.0e38f, d1 = 3.0e38f, d2 = 3.0e38f;
    int i0 = 0, i1 = 0, i2 = 0;
    for (int c = 0; c < N_COARSE; ++c) {
        // mirror reference: |f|^2 + |c|^2 - 2 f.c
        float d = pn2 + sn2[c] - 2.f * (px * scx[c] + py * scy[c]);
        if (d < d2) {
            if (d < d1) {
                d2 = d1; i2 = i1;
                if (d < d0) { d1 = d0; i1 = i0; d0 = d; i0 = c; }
                else       { d1 = d;  i1 = c; }
            } else { d2 = d; i2 = c; }
        }
    }
    float w0 = 1.f / fmaxf(d0, 1e-16f);
    float w1 = 1.f / fmaxf(d1, 1e-16f);
    float w2 = 1.f / fmaxf(d2, 1e-16f);
    float ws = w0 + w1 + w2;
    for (int j = 0; j < 3; ++j) {
        float v = w0 * cy[i0*3+j] + w1 * cy[i1*3+j] + w2 * cy[i2*3+j];
        fy[i*3+j] = v / ws;
    }
}

// ---------------- launch ----------------

extern "C" void kernel_launch(void* const* d_in, const int* in_sizes, int n_in,
                              void* d_out, int out_size, void* d_ws, size_t ws_size,
                              hipStream_t stream) {
    const float* x        = (const float*)d_in[0];
    const float* sdf      = (const float*)d_in[1];
    const float* coarse_x = (const float*)d_in[2];
    const float* coarse_y = (const float*)d_in[3];
    const int*   eidx     = (const int*)d_in[4];
    const float* pre_W0   = (const float*)d_in[5];
    const float* pre_b0   = (const float*)d_in[6];
    const float* pre_W1   = (const float*)d_in[7];
    const float* pre_b1   = (const float*)d_in[8];
    const float* pre_W2   = (const float*)d_in[9];
    const float* pre_b2   = (const float*)d_in[10];
    const float* end_W0   = (const float*)d_in[11];
    const float* end_b0   = (const float*)d_in[12];
    const float* end_W1   = (const float*)d_in[13];
    const float* end_b1   = (const float*)d_in[14];
    const float* end_W2   = (const float*)d_in[15];
    const float* end_b2   = (const float*)d_in[16];
    float* out = (float*)d_out;

    const int M = N_FINE, NE = N_EDGES;
    const int* erow = eidx;
    const int* ecol = eidx + NE;

    // workspace layout
    char* base = (char*)d_ws;
    size_t off = 0;
    auto alloc = [&](size_t bytes) { char* p = base + off; off = (off + bytes + 255) & ~(size_t)255; return p; };
    int*   counts = (int*)  alloc((size_t)M * 4);
    int*   rowptr = (int*)  alloc((size_t)(M + 1) * 4);
    int*   cursor = (int*)  alloc((size_t)M * 4);
    int*   esrc   = (int*)  alloc((size_t)NE * 4);
    float* dis    = (float*)alloc((size_t)M * 4);
    float* fy     = (float*)alloc((size_t)M * 3 * 4);
    float* B3     = (float*)alloc((size_t)M * 3 * 4);
    float* bufA   = (float*)alloc((size_t)M * 512 * 4);
    float* bufB   = (float*)alloc((size_t)M * 512 * 4);
    (void)ws_size;

    // CSR + degrees
    hipMemsetAsync(counts, 0, (size_t)M * 4, stream);
    count_edges_kernel<<<cdiv(NE, 256), 256, 0, stream>>>(ecol, counts, NE);
    compute_dis_kernel<<<cdiv(M, 256), 256, 0, stream>>>(counts, dis, M);
    scan_kernel<<<1, 1024, 0, stream>>>(counts, rowptr, M);
    hipMemcpyAsync(cursor, rowptr, (size_t)M * 4, hipMemcpyDeviceToDevice, stream);
    scatter_edges_kernel<<<cdiv(NE, 256), 256, 0, stream>>>(erow, ecol, cursor, esrc, NE);

    // KNN interpolate (independent)
    knn_kernel<<<cdiv(M, 256), 256, 0, stream>>>(x, coarse_x, coarse_y, fy, M);

    dim3 ggrid(cdiv(M, 64), 8);

    // pre0: [M,6]@[6,512]
    pre0_kernel<<<cdiv(M * 512, 256), 256, 0, stream>>>(x, sdf, pre_W0, dis, bufB, M);
    spmm512_kernel<<<M, 256, 0, stream>>>(bufB, rowptr, esrc, dis, pre_b0, bufA, 1);
    // pre1
    gemm512_kernel<<<ggrid, 256, 0, stream>>>(bufA, pre_W1, dis, bufB, M, nullptr, nullptr);
    spmm512_kernel<<<M, 256, 0, stream>>>(bufB, rowptr, esrc, dis, pre_b1, bufA, 1);
    // pre2
    gemm512_kernel<<<ggrid, 256, 0, stream>>>(bufA, pre_W2, dis, bufB, M, nullptr, nullptr);
    spmm512_kernel<<<M, 256, 0, stream>>>(bufB, rowptr, esrc, dis, pre_b2, bufA, 1);
    // end0: concat(fy[3], h[512]) @ end_W0[515,512]
    gemm512_kernel<<<ggrid, 256, 0, stream>>>(bufA, end_W0 + 3 * 512, dis, bufB, M, fy, end_W0);
    spmm512_kernel<<<M, 256, 0, stream>>>(bufB, rowptr, esrc, dis, end_b0, bufA, 1);
    // end1
    gemm512_kernel<<<ggrid, 256, 0, stream>>>(bufA, end_W1, dis, bufB, M, nullptr, nullptr);
    spmm512_kernel<<<M, 256, 0, stream>>>(bufB, rowptr, esrc, dis, end_b1, bufA, 1);
    // end2: [M,512]@[512,3], no relu
    gemm_n3_kernel<<<cdiv(M * 64, 256), 256, 0, stream>>>(bufA, end_W2, dis, B3, M);
    spmm3_kernel<<<cdiv(M, 256), 256, 0, stream>>>(B3, rowptr, esrc, dis, end_b2, out, M);
}

// Round 2
// 1027.220 us; speedup vs baseline: 2.1353x; 2.1353x over previous
//
#include <hip/hip_runtime.h>
#include <hip/hip_bf16.h>

#define N_FINE 50000
#define N_COARSE 2000
#define N_EDGES 300000

typedef short  s16x8 __attribute__((ext_vector_type(8)));
typedef float  f32x4 __attribute__((ext_vector_type(4)));

static inline int cdiv(int a, int b) { return (a + b - 1) / b; }

__device__ __forceinline__ short f2b(float f) {      // f32 -> bf16 RNE
    unsigned u = __builtin_bit_cast(unsigned, f);
    unsigned r = (u + 0x7fffu + ((u >> 16) & 1u)) >> 16;
    return (short)r;
}
__device__ __forceinline__ float b2f(short s) {
    return __builtin_bit_cast(float, ((unsigned)(unsigned short)s) << 16);
}

#define GL16(gsrc, ldst) __builtin_amdgcn_global_load_lds( \
    (const __attribute__((address_space(1))) unsigned*)(gsrc), \
    (__attribute__((address_space(3))) unsigned*)(ldst), 16, 0, 0)

// ---------------- CSR build ----------------

__global__ void count_edges_kernel(const int* __restrict__ col, int* __restrict__ counts, int ne) {
    int e = blockIdx.x * 256 + threadIdx.x;
    if (e < ne) atomicAdd(&counts[col[e]], 1);
}

__global__ void compute_dis_kernel(const int* __restrict__ counts, float* __restrict__ dis, int n) {
    int i = blockIdx.x * 256 + threadIdx.x;
    if (i < n) dis[i] = rsqrtf((float)(counts[i] + 1));   // +1 self loop
}

__global__ __launch_bounds__(1024) void scan_kernel(const int* __restrict__ counts, int* __restrict__ rowptr, int n) {
    __shared__ int buf[1024];
    __shared__ int carry_s;
    int tid = threadIdx.x;
    if (tid == 0) carry_s = 0;
    __syncthreads();
    for (int base = 0; base < n; base += 1024) {
        int i = base + tid;
        int v = (i < n) ? counts[i] : 0;
        buf[tid] = v;
        __syncthreads();
        for (int off = 1; off < 1024; off <<= 1) {
            int t = (tid >= off) ? buf[tid - off] : 0;
            __syncthreads();
            buf[tid] += t;
            __syncthreads();
        }
        int incl = buf[tid];
        int carry = carry_s;
        if (i < n) rowptr[i] = carry + incl - v;   // exclusive
        __syncthreads();
        if (tid == 0) carry_s = carry + buf[1023];
        __syncthreads();
    }
    if (tid == 0) rowptr[n] = carry_s;
}

__global__ void scatter_edges_kernel(const int* __restrict__ row, const int* __restrict__ col,
                                     int* __restrict__ cursor, int* __restrict__ esrc, int ne) {
    int e = blockIdx.x * 256 + threadIdx.x;
    if (e < ne) {
        int p = atomicAdd(&cursor[col[e]], 1);
        esrc[p] = row[e];
    }
}

// ---------------- weight prep: WT[n][k] = bf16(W[k][n]), 512x512 ----------------

__global__ void wt_kernel(const float* __restrict__ W, short* __restrict__ WT) {
    int idx = blockIdx.x * 256 + threadIdx.x;
    int n = idx >> 9, k = idx & 511;
    WT[(size_t)n * 512 + k] = f2b(W[(size_t)k * 512 + n]);
}

// ---------------- layer kernels ----------------

// first layer: [M,6] @ [6,512], scaled by dis, bf16 out
__global__ void pre0_kernel(const float* __restrict__ x, const float* __restrict__ sdf,
                            const float* __restrict__ W, const float* __restrict__ dis,
                            short* __restrict__ B, int M) {
    int idx = blockIdx.x * 256 + threadIdx.x;
    int m = idx >> 9, n = idx & 511;
    if (m >= M) return;
    float a0 = x[m*5+0], a1 = x[m*5+1], a2 = x[m*5+2], a3 = x[m*5+3], a4 = x[m*5+4], a5 = sdf[m];
    float t = a0*W[n] + a1*W[512+n] + a2*W[1024+n] + a3*W[1536+n] + a4*W[2048+n] + a5*W[2560+n];
    B[(size_t)m*512+n] = f2b(dis[m] * t);
}

// MFMA GEMM: C[M,512] = bf16( dis .* (A[M,512] @ W[512,512]  (+ A2[M,3]@W2[3,512]) ) )
// A bf16 [M,512] row-major; WT bf16 [512,512] = W transposed (WT[n][k]).
// 128x128 tile, BK=32, 4 waves (2x2), each wave 64x64 via 4x4 16x16x32 MFMA frags.
// LDS fragment-ordered: [rowBlock(8)][kchunk(4)][rowIn(16)][8 bf16] -> every
// ds_read_b128 is 64 consecutive 16B chunks (conflict-free), and global_load_lds
// dest stays linear (wave-uniform base + lane*16).
__global__ __launch_bounds__(256) void gemm512_mfma_kernel(
        const short* __restrict__ A, const short* __restrict__ WT,
        const float* __restrict__ dis, short* __restrict__ C, int M,
        const float* __restrict__ A2, const float* __restrict__ W2) {
    __shared__ __attribute__((aligned(16))) short As[4096];   // 8 KB
    __shared__ __attribute__((aligned(16))) short Bs[4096];   // 8 KB
    int tid  = threadIdx.x;
    int lane = tid & 63;
    int w    = tid >> 6;
    int wr   = w >> 1, wc = w & 1;
    int row0 = blockIdx.x * 128;
    int col0 = blockIdx.y * 128;

    // staging: wave w fills rowBlocks 2w and 2w+1 of both tiles
    int rb0 = 2 * w, rb1 = 2 * w + 1;
    int rIn = lane & 15, kc = lane >> 4;
    int ar0 = row0 + rb0 * 16 + rIn; if (ar0 >= M) ar0 = M - 1;
    int ar1 = row0 + rb1 * 16 + rIn; if (ar1 >= M) ar1 = M - 1;
    const short* aSrc0 = A  + (size_t)ar0 * 512 + kc * 8;
    const short* aSrc1 = A  + (size_t)ar1 * 512 + kc * 8;
    const short* bSrc0 = WT + (size_t)(col0 + rb0 * 16 + rIn) * 512 + kc * 8;
    const short* bSrc1 = WT + (size_t)(col0 + rb1 * 16 + rIn) * 512 + kc * 8;
    short* aDst0 = &As[rb0 * 512];   // wave-uniform LDS bases
    short* aDst1 = &As[rb1 * 512];
    short* bDst0 = &Bs[rb0 * 512];
    short* bDst1 = &Bs[rb1 * 512];

    f32x4 acc[4][4] = {};
    const s16x8* aFrag[4];
    const s16x8* bFrag[4];
#pragma unroll
    for (int mi = 0; mi < 4; ++mi) aFrag[mi] = (const s16x8*)&As[(wr * 4 + mi) * 512 + lane * 8];
#pragma unroll
    for (int ni = 0; ni < 4; ++ni) bFrag[ni] = (const s16x8*)&Bs[(wc * 4 + ni) * 512 + lane * 8];

    for (int k0 = 0; k0 < 512; k0 += 32) {
        GL16(aSrc0 + k0, aDst0);
        GL16(aSrc1 + k0, aDst1);
        GL16(bSrc0 + k0, bDst0);
        GL16(bSrc1 + k0, bDst1);
        __syncthreads();
        s16x8 av[4], bv[4];
#pragma unroll
        for (int mi = 0; mi < 4; ++mi) av[mi] = *aFrag[mi];
#pragma unroll
        for (int ni = 0; ni < 4; ++ni) bv[ni] = *bFrag[ni];
#pragma unroll
        for (int mi = 0; mi < 4; ++mi)
#pragma unroll
            for (int ni = 0; ni < 4; ++ni)
                acc[mi][ni] = __builtin_amdgcn_mfma_f32_16x16x32_bf16(av[mi], bv[ni], acc[mi][ni], 0, 0, 0);
        __syncthreads();
    }

    int rbase = row0 + wr * 64;
    int cbase = col0 + wc * 64;
#pragma unroll
    for (int mi = 0; mi < 4; ++mi) {
#pragma unroll
        for (int r = 0; r < 4; ++r) {
            int row = rbase + mi * 16 + (lane >> 4) * 4 + r;
            if (row >= M) continue;
            float d = dis[row];
            float a20 = 0.f, a21 = 0.f, a22 = 0.f;
            if (A2) { a20 = A2[row*3+0]; a21 = A2[row*3+1]; a22 = A2[row*3+2]; }
#pragma unroll
            for (int ni = 0; ni < 4; ++ni) {
                int col = cbase + ni * 16 + (lane & 15);
                float v = acc[mi][ni][r];
                if (A2) v += a20 * W2[col] + a21 * W2[512 + col] + a22 * W2[1024 + col];
                C[(size_t)row * 512 + col] = f2b(d * v);
            }
        }
    }
}

// out[i,:] = bf16(relu( dis[i]*(sum_nbr B[src,:] + B[i,:]) + bias ))  -- one wave/node
__global__ __launch_bounds__(256) void spmm512_kernel(
        const short* __restrict__ B, const int* __restrict__ rowptr, const int* __restrict__ esrc,
        const float* __restrict__ dis, const float* __restrict__ bias,
        short* __restrict__ out, int M) {
    int node = blockIdx.x * 4 + (threadIdx.x >> 6);
    int lane = threadIdx.x & 63;
    if (node >= M) return;
    const s16x8* Bv = (const s16x8*)B;
    s16x8 v = Bv[(size_t)node * 64 + lane];   // self loop
    float acc[8];
#pragma unroll
    for (int j = 0; j < 8; ++j) acc[j] = b2f(v[j]);
    int s = rowptr[node], e = rowptr[node + 1];
    for (int p = s; p < e; ++p) {
        int src = esrc[p];
        s16x8 t = Bv[(size_t)src * 64 + lane];
#pragma unroll
        for (int j = 0; j < 8; ++j) acc[j] += b2f(t[j]);
    }
    float d = dis[node];
    const float4* bp = (const float4*)bias;
    float4 b0 = bp[lane * 2], b1 = bp[lane * 2 + 1];
    float r[8];
    r[0] = d*acc[0] + b0.x; r[1] = d*acc[1] + b0.y; r[2] = d*acc[2] + b0.z; r[3] = d*acc[3] + b0.w;
    r[4] = d*acc[4] + b1.x; r[5] = d*acc[5] + b1.y; r[6] = d*acc[6] + b1.z; r[7] = d*acc[7] + b1.w;
    s16x8 o;
#pragma unroll
    for (int j = 0; j < 8; ++j) o[j] = f2b(fmaxf(r[j], 0.f));
    ((s16x8*)out)[(size_t)node * 64 + lane] = o;
}

// final GEMM: B3[M,3] = dis .* (A_bf16[M,512] @ W[512,3]); one wave per row
__global__ __launch_bounds__(256) void gemm_n3_kernel(
        const short* __restrict__ A, const float* __restrict__ W,
        const float* __restrict__ dis, float* __restrict__ B3, int M) {
    int wid = (blockIdx.x * 256 + threadIdx.x) >> 6;
    int lane = threadIdx.x & 63;
    if (wid >= M) return;
    s16x8 v = ((const s16x8*)A)[(size_t)wid * 64 + lane];
    float s0 = 0.f, s1 = 0.f, s2 = 0.f;
#pragma unroll
    for (int j = 0; j < 8; ++j) {
        float a = b2f(v[j]);
        int k = lane * 8 + j;
        s0 += a * W[k*3+0];
        s1 += a * W[k*3+1];
        s2 += a * W[k*3+2];
    }
    for (int off = 32; off > 0; off >>= 1) {
        s0 += __shfl_down(s0, off);
        s1 += __shfl_down(s1, off);
        s2 += __shfl_down(s2, off);
    }
    if (lane == 0) {
        float d = dis[wid];
        B3[wid*3+0] = d * s0;
        B3[wid*3+1] = d * s1;
        B3[wid*3+2] = d * s2;
    }
}

__global__ void spmm3_kernel(const float* __restrict__ B3, const int* __restrict__ rowptr,
                             const int* __restrict__ esrc, const float* __restrict__ dis,
                             const float* __restrict__ bias, float* __restrict__ out, int M) {
    int i = blockIdx.x * 256 + threadIdx.x;
    if (i >= M) return;
    float a0 = B3[i*3+0], a1 = B3[i*3+1], a2 = B3[i*3+2];
    int s = rowptr[i], e = rowptr[i + 1];
    for (int p = s; p < e; ++p) {
        int src = esrc[p];
        a0 += B3[src*3+0];
        a1 += B3[src*3+1];
        a2 += B3[src*3+2];
    }
    float d = dis[i];
    out[i*3+0] = d * a0 + bias[0];
    out[i*3+1] = d * a1 + bias[1];
    out[i*3+2] = d * a2 + bias[2];
}

// KNN interpolate (ref-identical distance formula)
__global__ __launch_bounds__(256) void knn_kernel(
        const float* __restrict__ x, const float* __restrict__ cpos,
        const float* __restrict__ cy, float* __restrict__ fy, int M) {
    __shared__ float scx[N_COARSE];
    __shared__ float scy[N_COARSE];
    __shared__ float sn2[N_COARSE];
    for (int t = threadIdx.x; t < N_COARSE; t += 256) {
        float a = cpos[t*2+0], b = cpos[t*2+1];
        scx[t] = a; scy[t] = b; sn2[t] = a*a + b*b;
    }
    __syncthreads();
    int i = blockIdx.x * 256 + threadIdx.x;
    if (i >= M) return;
    float px = x[i*5+0], py = x[i*5+1];
    float pn2 = px*px + py*py;
    float d0 = 3.0e38f, d1 = 3.0e38f, d2 = 3.0e38f;
    int i0 = 0, i1 = 0, i2 = 0;
    for (int c = 0; c < N_COARSE; ++c) {
        float d = pn2 + sn2[c] - 2.f * (px * scx[c] + py * scy[c]);
        if (d < d2) {
            if (d < d1) {
                d2 = d1; i2 = i1;
                if (d < d0) { d1 = d0; i1 = i0; d0 = d; i0 = c; }
                else       { d1 = d;  i1 = c; }
            } else { d2 = d; i2 = c; }
        }
    }
    float w0 = 1.f / fmaxf(d0, 1e-16f);
    float w1 = 1.f / fmaxf(d1, 1e-16f);
    float w2 = 1.f / fmaxf(d2, 1e-16f);
    float ws = w0 + w1 + w2;
    for (int j = 0; j < 3; ++j) {
        float v = w0 * cy[i0*3+j] + w1 * cy[i1*3+j] + w2 * cy[i2*3+j];
        fy[i*3+j] = v / ws;
    }
}

// ---------------- launch ----------------

extern "C" void kernel_launch(void* const* d_in, const int* in_sizes, int n_in,
                              void* d_out, int out_size, void* d_ws, size_t ws_size,
                              hipStream_t stream) {
    const float* x        = (const float*)d_in[0];
    const float* sdf      = (const float*)d_in[1];
    const float* coarse_x = (const float*)d_in[2];
    const float* coarse_y = (const float*)d_in[3];
    const int*   eidx     = (const int*)d_in[4];
    const float* pre_W0   = (const float*)d_in[5];
    const float* pre_b0   = (const float*)d_in[6];
    const float* pre_W1   = (const float*)d_in[7];
    const float* pre_b1   = (const float*)d_in[8];
    const float* pre_W2   = (const float*)d_in[9];
    const float* pre_b2   = (const float*)d_in[10];
    const float* end_W0   = (const float*)d_in[11];
    const float* end_b0   = (const float*)d_in[12];
    const float* end_W1   = (const float*)d_in[13];
    const float* end_b1   = (const float*)d_in[14];
    const float* end_W2   = (const float*)d_in[15];
    const float* end_b2   = (const float*)d_in[16];
    float* out = (float*)d_out;

    const int M = N_FINE, NE = N_EDGES;
    const int* erow = eidx;
    const int* ecol = eidx + NE;

    char* base = (char*)d_ws;
    size_t off = 0;
    auto alloc = [&](size_t bytes) { char* p = base + off; off = (off + bytes + 255) & ~(size_t)255; return p; };
    int*   counts = (int*)  alloc((size_t)M * 4);
    int*   rowptr = (int*)  alloc((size_t)(M + 1) * 4);
    int*   cursor = (int*)  alloc((size_t)M * 4);
    int*   esrc   = (int*)  alloc((size_t)NE * 4);
    float* dis    = (float*)alloc((size_t)M * 4);
    float* fy     = (float*)alloc((size_t)M * 3 * 4);
    float* B3     = (float*)alloc((size_t)M * 3 * 4);
    short* WT1    = (short*)alloc((size_t)512 * 512 * 2);
    short* WT2    = (short*)alloc((size_t)512 * 512 * 2);
    short* WT3    = (short*)alloc((size_t)512 * 512 * 2);
    short* WT4    = (short*)alloc((size_t)512 * 512 * 2);
    short* bufA   = (short*)alloc((size_t)M * 512 * 2);
    short* bufB   = (short*)alloc((size_t)M * 512 * 2);
    (void)ws_size;

    // weight prep (independent)
    wt_kernel<<<1024, 256, 0, stream>>>(pre_W1, WT1);
    wt_kernel<<<1024, 256, 0, stream>>>(pre_W2, WT2);
    wt_kernel<<<1024, 256, 0, stream>>>(end_W0 + 3 * 512, WT3);   // h-part rows 3..514
    wt_kernel<<<1024, 256, 0, stream>>>(end_W1, WT4);

    // CSR + degrees
    hipMemsetAsync(counts, 0, (size_t)M * 4, stream);
    count_edges_kernel<<<cdiv(NE, 256), 256, 0, stream>>>(ecol, counts, NE);
    compute_dis_kernel<<<cdiv(M, 256), 256, 0, stream>>>(counts, dis, M);
    scan_kernel<<<1, 1024, 0, stream>>>(counts, rowptr, M);
    hipMemcpyAsync(cursor, rowptr, (size_t)M * 4, hipMemcpyDeviceToDevice, stream);
    scatter_edges_kernel<<<cdiv(NE, 256), 256, 0, stream>>>(erow, ecol, cursor, esrc, NE);

    // KNN interpolate (independent)
    knn_kernel<<<cdiv(M, 256), 256, 0, stream>>>(x, coarse_x, coarse_y, fy, M);

    dim3 ggrid(cdiv(M, 128), 4);
    int sgrid = cdiv(M, 4);

    pre0_kernel<<<cdiv(M * 512, 256), 256, 0, stream>>>(x, sdf, pre_W0, dis, bufB, M);
    spmm512_kernel<<<sgrid, 256, 0, stream>>>(bufB, rowptr, esrc, dis, pre_b0, bufA, M);

    gemm512_mfma_kernel<<<ggrid, 256, 0, stream>>>(bufA, WT1, dis, bufB, M, nullptr, nullptr);
    spmm512_kernel<<<sgrid, 256, 0, stream>>>(bufB, rowptr, esrc, dis, pre_b1, bufA, M);

    gemm512_mfma_kernel<<<ggrid, 256, 0, stream>>>(bufA, WT2, dis, bufB, M, nullptr, nullptr);
    spmm512_kernel<<<sgrid, 256, 0, stream>>>(bufB, rowptr, esrc, dis, pre_b2, bufA, M);

    gemm512_mfma_kernel<<<ggrid, 256, 0, stream>>>(bufA, WT3, dis, bufB, M, fy, end_W0);
    spmm512_kernel<<<sgrid, 256, 0, stream>>>(bufB, rowptr, esrc, dis, end_b0, bufA, M);

    gemm512_mfma_kernel<<<ggrid, 256, 0, stream>>>(bufA, WT4, dis, bufB, M, nullptr, nullptr);
    spmm512_kernel<<<sgrid, 256, 0, stream>>>(bufB, rowptr, esrc, dis, end_b1, bufA, M);

    gemm_n3_kernel<<<cdiv(M * 64, 256), 256, 0, stream>>>(bufA, end_W2, dis, B3, M);
    spmm3_kernel<<<cdiv(M, 256), 256, 0, stream>>>(B3, rowptr, esrc, dis, end_b2, out, M);
}

// Round 3
// 871.178 us; speedup vs baseline: 2.5178x; 1.1791x over previous
//
#include <hip/hip_runtime.h>
#include <hip/hip_bf16.h>

#define N_FINE 50000
#define N_COARSE 2000
#define N_EDGES 300000

typedef short  s16x8 __attribute__((ext_vector_type(8)));
typedef float  f32x4 __attribute__((ext_vector_type(4)));

static inline int cdiv(int a, int b) { return (a + b - 1) / b; }

__device__ __forceinline__ short f2b(float f) {      // f32 -> bf16 RNE
    unsigned u = __builtin_bit_cast(unsigned, f);
    unsigned r = (u + 0x7fffu + ((u >> 16) & 1u)) >> 16;
    return (short)r;
}
__device__ __forceinline__ float b2f(short s) {
    return __builtin_bit_cast(float, ((unsigned)(unsigned short)s) << 16);
}

#define GL16(gsrc, ldst) __builtin_amdgcn_global_load_lds( \
    (const __attribute__((address_space(1))) unsigned*)(gsrc), \
    (__attribute__((address_space(3))) unsigned*)(ldst), 16, 0, 0)

// ---------------- CSR build ----------------

__global__ void count_edges_kernel(const int* __restrict__ col, int* __restrict__ counts, int ne) {
    int e = blockIdx.x * 256 + threadIdx.x;
    if (e < ne) atomicAdd(&counts[col[e]], 1);
}

__global__ void compute_dis_kernel(const int* __restrict__ counts, float* __restrict__ dis, int n) {
    int i = blockIdx.x * 256 + threadIdx.x;
    if (i < n) dis[i] = rsqrtf((float)(counts[i] + 1));   // +1 self loop
}

// two-level scan: per-block 1024-wide exclusive scan + block totals
__global__ __launch_bounds__(1024) void scan_block_kernel(const int* __restrict__ counts,
        int* __restrict__ rowptr, int* __restrict__ blksum, int n) {
    __shared__ int wsum[16];
    int tid = threadIdx.x, lane = tid & 63, wv = tid >> 6;
    int i = blockIdx.x * 1024 + tid;
    int v = (i < n) ? counts[i] : 0;
    int x = v;
#pragma unroll
    for (int off = 1; off < 64; off <<= 1) {
        int t = __shfl_up(x, off);
        if (lane >= off) x += t;
    }
    if (lane == 63) wsum[wv] = x;
    __syncthreads();
    if (wv == 0) {
        int s = (lane < 16) ? wsum[lane] : 0;
#pragma unroll
        for (int off = 1; off < 16; off <<= 1) {
            int t = __shfl_up(s, off);
            if (lane >= off) s += t;
        }
        if (lane < 16) wsum[lane] = s;
    }
    __syncthreads();
    int prefix = (wv > 0) ? wsum[wv - 1] : 0;
    int incl = prefix + x;
    if (i < n) rowptr[i] = incl - v;   // exclusive
    if (tid == 1023) blksum[blockIdx.x] = incl;
}

// scan <=64 block sums in one wave, exclusive in-place
__global__ void scan_tops_kernel(int* __restrict__ blksum, int nb) {
    int lane = threadIdx.x;
    int v = (lane < nb) ? blksum[lane] : 0;
    int x = v;
#pragma unroll
    for (int off = 1; off < 64; off <<= 1) {
        int t = __shfl_up(x, off);
        if (lane >= off) x += t;
    }
    if (lane < nb) blksum[lane] = x - v;
}

__global__ void scan_add_kernel(int* __restrict__ rowptr, const int* __restrict__ blksum, int n) {
    int i = blockIdx.x * 256 + threadIdx.x;
    if (i < n) rowptr[i] += blksum[i >> 10];
    else if (i == n) rowptr[n] = N_EDGES;
}

__global__ void scatter_edges_kernel(const int* __restrict__ row, const int* __restrict__ col,
                                     int* __restrict__ cursor, int* __restrict__ esrc, int ne) {
    int e = blockIdx.x * 256 + threadIdx.x;
    if (e < ne) {
        int p = atomicAdd(&cursor[col[e]], 1);
        esrc[p] = row[e];
    }
}

// ---------------- weight prep: WT[n][k] = bf16(W[k][n]), 512x512 ----------------

__global__ void wt_kernel(const float* __restrict__ W, short* __restrict__ WT) {
    int idx = blockIdx.x * 256 + threadIdx.x;
    int n = idx >> 9, k = idx & 511;
    WT[(size_t)n * 512 + k] = f2b(W[(size_t)k * 512 + n]);
}

// ---------------- layer kernels ----------------

// first layer: [M,6] @ [6,512], scaled by dis, bf16 out
__global__ void pre0_kernel(const float* __restrict__ x, const float* __restrict__ sdf,
                            const float* __restrict__ W, const float* __restrict__ dis,
                            short* __restrict__ B, int M) {
    int idx = blockIdx.x * 256 + threadIdx.x;
    int m = idx >> 9, n = idx & 511;
    if (m >= M) return;
    float a0 = x[m*5+0], a1 = x[m*5+1], a2 = x[m*5+2], a3 = x[m*5+3], a4 = x[m*5+4], a5 = sdf[m];
    float t = a0*W[n] + a1*W[512+n] + a2*W[1024+n] + a3*W[1536+n] + a4*W[2048+n] + a5*W[2560+n];
    B[(size_t)m*512+n] = f2b(dis[m] * t);
}

// MFMA GEMM: C[M,512] = bf16( dis .* (A[M,512] @ W[512,512]  (+ A2[M,3]@W2[3,512]) ) )
__global__ __launch_bounds__(256) void gemm512_mfma_kernel(
        const short* __restrict__ A, const short* __restrict__ WT,
        const float* __restrict__ dis, short* __restrict__ C, int M,
        const float* __restrict__ A2, const float* __restrict__ W2) {
    __shared__ __attribute__((aligned(16))) short As[4096];   // 8 KB
    __shared__ __attribute__((aligned(16))) short Bs[4096];   // 8 KB
    int tid  = threadIdx.x;
    int lane = tid & 63;
    int w    = tid >> 6;
    int wr   = w >> 1, wc = w & 1;
    int row0 = blockIdx.x * 128;
    int col0 = blockIdx.y * 128;

    int rb0 = 2 * w, rb1 = 2 * w + 1;
    int rIn = lane & 15, kc = lane >> 4;
    int ar0 = row0 + rb0 * 16 + rIn; if (ar0 >= M) ar0 = M - 1;
    int ar1 = row0 + rb1 * 16 + rIn; if (ar1 >= M) ar1 = M - 1;
    const short* aSrc0 = A  + (size_t)ar0 * 512 + kc * 8;
    const short* aSrc1 = A  + (size_t)ar1 * 512 + kc * 8;
    const short* bSrc0 = WT + (size_t)(col0 + rb0 * 16 + rIn) * 512 + kc * 8;
    const short* bSrc1 = WT + (size_t)(col0 + rb1 * 16 + rIn) * 512 + kc * 8;
    short* aDst0 = &As[rb0 * 512];
    short* aDst1 = &As[rb1 * 512];
    short* bDst0 = &Bs[rb0 * 512];
    short* bDst1 = &Bs[rb1 * 512];

    f32x4 acc[4][4] = {};
    const s16x8* aFrag[4];
    const s16x8* bFrag[4];
#pragma unroll
    for (int mi = 0; mi < 4; ++mi) aFrag[mi] = (const s16x8*)&As[(wr * 4 + mi) * 512 + lane * 8];
#pragma unroll
    for (int ni = 0; ni < 4; ++ni) bFrag[ni] = (const s16x8*)&Bs[(wc * 4 + ni) * 512 + lane * 8];

    for (int k0 = 0; k0 < 512; k0 += 32) {
        GL16(aSrc0 + k0, aDst0);
        GL16(aSrc1 + k0, aDst1);
        GL16(bSrc0 + k0, bDst0);
        GL16(bSrc1 + k0, bDst1);
        __syncthreads();
        s16x8 av[4], bv[4];
#pragma unroll
        for (int mi = 0; mi < 4; ++mi) av[mi] = *aFrag[mi];
#pragma unroll
        for (int ni = 0; ni < 4; ++ni) bv[ni] = *bFrag[ni];
#pragma unroll
        for (int mi = 0; mi < 4; ++mi)
#pragma unroll
            for (int ni = 0; ni < 4; ++ni)
                acc[mi][ni] = __builtin_amdgcn_mfma_f32_16x16x32_bf16(av[mi], bv[ni], acc[mi][ni], 0, 0, 0);
        __syncthreads();
    }

    int rbase = row0 + wr * 64;
    int cbase = col0 + wc * 64;
#pragma unroll
    for (int mi = 0; mi < 4; ++mi) {
#pragma unroll
        for (int r = 0; r < 4; ++r) {
            int row = rbase + mi * 16 + (lane >> 4) * 4 + r;
            if (row >= M) continue;
            float d = dis[row];
            float a20 = 0.f, a21 = 0.f, a22 = 0.f;
            if (A2) { a20 = A2[row*3+0]; a21 = A2[row*3+1]; a22 = A2[row*3+2]; }
#pragma unroll
            for (int ni = 0; ni < 4; ++ni) {
                int col = cbase + ni * 16 + (lane & 15);
                float v = acc[mi][ni][r];
                if (A2) v += a20 * W2[col] + a21 * W2[512 + col] + a22 * W2[1024 + col];
                C[(size_t)row * 512 + col] = f2b(d * v);
            }
        }
    }
}

// out[i,:] = bf16(relu( dis[i]*(sum_nbr B[src,:] + B[i,:]) + bias ))  -- one wave/node
__global__ __launch_bounds__(256) void spmm512_kernel(
        const short* __restrict__ B, const int* __restrict__ rowptr, const int* __restrict__ esrc,
        const float* __restrict__ dis, const float* __restrict__ bias,
        short* __restrict__ out, int M) {
    int node = blockIdx.x * 4 + (threadIdx.x >> 6);
    int lane = threadIdx.x & 63;
    if (node >= M) return;
    const s16x8* Bv = (const s16x8*)B;
    s16x8 v = Bv[(size_t)node * 64 + lane];   // self loop
    float acc[8];
#pragma unroll
    for (int j = 0; j < 8; ++j) acc[j] = b2f(v[j]);
    int s = rowptr[node], e = rowptr[node + 1];
    for (int p = s; p < e; ++p) {
        int src = esrc[p];
        s16x8 t = Bv[(size_t)src * 64 + lane];
#pragma unroll
        for (int j = 0; j < 8; ++j) acc[j] += b2f(t[j]);
    }
    float d = dis[node];
    const float4* bp = (const float4*)bias;
    float4 b0 = bp[lane * 2], b1 = bp[lane * 2 + 1];
    float r[8];
    r[0] = d*acc[0] + b0.x; r[1] = d*acc[1] + b0.y; r[2] = d*acc[2] + b0.z; r[3] = d*acc[3] + b0.w;
    r[4] = d*acc[4] + b1.x; r[5] = d*acc[5] + b1.y; r[6] = d*acc[6] + b1.z; r[7] = d*acc[7] + b1.w;
    s16x8 o;
#pragma unroll
    for (int j = 0; j < 8; ++j) o[j] = f2b(fmaxf(r[j], 0.f));
    ((s16x8*)out)[(size_t)node * 64 + lane] = o;
}

// final GEMM: B3[M,3] = dis .* (A_bf16[M,512] @ W[512,3]); one wave per row
__global__ __launch_bounds__(256) void gemm_n3_kernel(
        const short* __restrict__ A, const float* __restrict__ W,
        const float* __restrict__ dis, float* __restrict__ B3, int M) {
    int wid = (blockIdx.x * 256 + threadIdx.x) >> 6;
    int lane = threadIdx.x & 63;
    if (wid >= M) return;
    s16x8 v = ((const s16x8*)A)[(size_t)wid * 64 + lane];
    float s0 = 0.f, s1 = 0.f, s2 = 0.f;
#pragma unroll
    for (int j = 0; j < 8; ++j) {
        float a = b2f(v[j]);
        int k = lane * 8 + j;
        s0 += a * W[k*3+0];
        s1 += a * W[k*3+1];
        s2 += a * W[k*3+2];
    }
    for (int off = 32; off > 0; off >>= 1) {
        s0 += __shfl_down(s0, off);
        s1 += __shfl_down(s1, off);
        s2 += __shfl_down(s2, off);
    }
    if (lane == 0) {
        float d = dis[wid];
        B3[wid*3+0] = d * s0;
        B3[wid*3+1] = d * s1;
        B3[wid*3+2] = d * s2;
    }
}

__global__ void spmm3_kernel(const float* __restrict__ B3, const int* __restrict__ rowptr,
                             const int* __restrict__ esrc, const float* __restrict__ dis,
                             const float* __restrict__ bias, float* __restrict__ out, int M) {
    int i = blockIdx.x * 256 + threadIdx.x;
    if (i >= M) return;
    float a0 = B3[i*3+0], a1 = B3[i*3+1], a2 = B3[i*3+2];
    int s = rowptr[i], e = rowptr[i + 1];
    for (int p = s; p < e; ++p) {
        int src = esrc[p];
        a0 += B3[src*3+0];
        a1 += B3[src*3+1];
        a2 += B3[src*3+2];
    }
    float d = dis[i];
    out[i*3+0] = d * a0 + bias[0];
    out[i*3+1] = d * a1 + bias[1];
    out[i*3+2] = d * a2 + bias[2];
}

// KNN interpolate: block = 64 fine nodes x 4 waves; wave w scans coarse chunk of 500.
// Per-thread top-3, then (d,idx)-lexicographic merge of 12 candidates (matches top_k ties).
__global__ __launch_bounds__(256) void knn_kernel(
        const float* __restrict__ x, const float* __restrict__ cpos,
        const float* __restrict__ cy, float* __restrict__ fy, int M) {
    __shared__ float sd[12][64];
    __shared__ int   si[12][64];
    int lane = threadIdx.x & 63;
    int w = threadIdx.x >> 6;
    int gi = blockIdx.x * 64 + lane;
    int i = (gi < M) ? gi : (M - 1);
    float px = x[i*5+0], py = x[i*5+1];
    float pn2 = px*px + py*py;
    float d0 = 3.0e38f, d1 = 3.0e38f, d2 = 3.0e38f;
    int i0 = 0x7fffffff, i1 = 0x7fffffff, i2 = 0x7fffffff;
    int c0 = w * (N_COARSE / 4), c1 = c0 + (N_COARSE / 4);
    for (int c = c0; c < c1; ++c) {
        float a = cpos[c*2+0], b = cpos[c*2+1];
        float sn2 = a*a + b*b;                       // ref formula
        float d = pn2 + sn2 - 2.f * (px * a + py * b);
        if (d < d2) {
            if (d < d1) {
                d2 = d1; i2 = i1;
                if (d < d0) { d1 = d0; i1 = i0; d0 = d; i0 = c; }
                else       { d1 = d;  i1 = c; }
            } else { d2 = d; i2 = c; }
        }
    }
    sd[w*3+0][lane] = d0; si[w*3+0][lane] = i0;
    sd[w*3+1][lane] = d1; si[w*3+1][lane] = i1;
    sd[w*3+2][lane] = d2; si[w*3+2][lane] = i2;
    __syncthreads();
    if (w != 0 || gi >= M) return;
    float cd[12]; int ci[12];
#pragma unroll
    for (int q = 0; q < 12; ++q) { cd[q] = sd[q][lane]; ci[q] = si[q][lane]; }
    float bd[3]; int bi[3];
#pragma unroll
    for (int s = 0; s < 3; ++s) {
        float best = 3.4e38f; int besti = 0x7fffffff; int bq = 0;
#pragma unroll
        for (int q = 0; q < 12; ++q) {
            bool better = (cd[q] < best) || (cd[q] == best && ci[q] < besti);
            if (better) { best = cd[q]; besti = ci[q]; bq = q; }
        }
        bd[s] = best; bi[s] = besti;
        cd[bq] = 3.4e38f; ci[bq] = 0x7fffffff;
    }
    float w0 = 1.f / fmaxf(bd[0], 1e-16f);
    float w1 = 1.f / fmaxf(bd[1], 1e-16f);
    float w2 = 1.f / fmaxf(bd[2], 1e-16f);
    float ws = w0 + w1 + w2;
    int j0 = bi[0], j1 = bi[1], j2 = bi[2];
#pragma unroll
    for (int j = 0; j < 3; ++j) {
        float v = w0 * cy[j0*3+j] + w1 * cy[j1*3+j] + w2 * cy[j2*3+j];
        fy[gi*3+j] = v / ws;
    }
}

// ---------------- launch ----------------

extern "C" void kernel_launch(void* const* d_in, const int* in_sizes, int n_in,
                              void* d_out, int out_size, void* d_ws, size_t ws_size,
                              hipStream_t stream) {
    const float* x        = (const float*)d_in[0];
    const float* sdf      = (const float*)d_in[1];
    const float* coarse_x = (const float*)d_in[2];
    const float* coarse_y = (const float*)d_in[3];
    const int*   eidx     = (const int*)d_in[4];
    const float* pre_W0   = (const float*)d_in[5];
    const float* pre_b0   = (const float*)d_in[6];
    const float* pre_W1   = (const float*)d_in[7];
    const float* pre_b1   = (const float*)d_in[8];
    const float* pre_W2   = (const float*)d_in[9];
    const float* pre_b2   = (const float*)d_in[10];
    const float* end_W0   = (const float*)d_in[11];
    const float* end_b0   = (const float*)d_in[12];
    const float* end_W1   = (const float*)d_in[13];
    const float* end_b1   = (const float*)d_in[14];
    const float* end_W2   = (const float*)d_in[15];
    const float* end_b2   = (const float*)d_in[16];
    float* out = (float*)d_out;

    const int M = N_FINE, NE = N_EDGES;
    const int* erow = eidx;
    const int* ecol = eidx + NE;

    char* base = (char*)d_ws;
    size_t off = 0;
    auto alloc = [&](size_t bytes) { char* p = base + off; off = (off + bytes + 255) & ~(size_t)255; return p; };
    int*   counts = (int*)  alloc((size_t)M * 4);
    int*   rowptr = (int*)  alloc((size_t)(M + 1) * 4);
    int*   cursor = (int*)  alloc((size_t)M * 4);
    int*   esrc   = (int*)  alloc((size_t)NE * 4);
    int*   blksum = (int*)  alloc((size_t)64 * 4);
    float* dis    = (float*)alloc((size_t)M * 4);
    float* fy     = (float*)alloc((size_t)M * 3 * 4);
    float* B3     = (float*)alloc((size_t)M * 3 * 4);
    short* WT1    = (short*)alloc((size_t)512 * 512 * 2);
    short* WT2    = (short*)alloc((size_t)512 * 512 * 2);
    short* WT3    = (short*)alloc((size_t)512 * 512 * 2);
    short* WT4    = (short*)alloc((size_t)512 * 512 * 2);
    short* bufA   = (short*)alloc((size_t)M * 512 * 2);
    short* bufB   = (short*)alloc((size_t)M * 512 * 2);
    (void)ws_size;

    // weight prep (independent)
    wt_kernel<<<1024, 256, 0, stream>>>(pre_W1, WT1);
    wt_kernel<<<1024, 256, 0, stream>>>(pre_W2, WT2);
    wt_kernel<<<1024, 256, 0, stream>>>(end_W0 + 3 * 512, WT3);   // h-part rows 3..514
    wt_kernel<<<1024, 256, 0, stream>>>(end_W1, WT4);

    // CSR + degrees
    hipMemsetAsync(counts, 0, (size_t)M * 4, stream);
    count_edges_kernel<<<cdiv(NE, 256), 256, 0, stream>>>(ecol, counts, NE);
    compute_dis_kernel<<<cdiv(M, 256), 256, 0, stream>>>(counts, dis, M);
    int nb = cdiv(M, 1024);
    scan_block_kernel<<<nb, 1024, 0, stream>>>(counts, rowptr, blksum, M);
    scan_tops_kernel<<<1, 64, 0, stream>>>(blksum, nb);
    scan_add_kernel<<<cdiv(M + 1, 256), 256, 0, stream>>>(rowptr, blksum, M);
    hipMemcpyAsync(cursor, rowptr, (size_t)M * 4, hipMemcpyDeviceToDevice, stream);
    scatter_edges_kernel<<<cdiv(NE, 256), 256, 0, stream>>>(erow, ecol, cursor, esrc, NE);

    // KNN interpolate
    knn_kernel<<<cdiv(M, 64), 256, 0, stream>>>(x, coarse_x, coarse_y, fy, M);

    dim3 ggrid(cdiv(M, 128), 4);
    int sgrid = cdiv(M, 4);

    pre0_kernel<<<cdiv(M * 512, 256), 256, 0, stream>>>(x, sdf, pre_W0, dis, bufB, M);
    spmm512_kernel<<<sgrid, 256, 0, stream>>>(bufB, rowptr, esrc, dis, pre_b0, bufA, M);

    gemm512_mfma_kernel<<<ggrid, 256, 0, stream>>>(bufA, WT1, dis, bufB, M, nullptr, nullptr);
    spmm512_kernel<<<sgrid, 256, 0, stream>>>(bufB, rowptr, esrc, dis, pre_b1, bufA, M);

    gemm512_mfma_kernel<<<ggrid, 256, 0, stream>>>(bufA, WT2, dis, bufB, M, nullptr, nullptr);
    spmm512_kernel<<<sgrid, 256, 0, stream>>>(bufB, rowptr, esrc, dis, pre_b2, bufA, M);

    gemm512_mfma_kernel<<<ggrid, 256, 0, stream>>>(bufA, WT3, dis, bufB, M, fy, end_W0);
    spmm512_kernel<<<sgrid, 256, 0, stream>>>(bufB, rowptr, esrc, dis, end_b0, bufA, M);

    gemm512_mfma_kernel<<<ggrid, 256, 0, stream>>>(bufA, WT4, dis, bufB, M, nullptr, nullptr);
    spmm512_kernel<<<sgrid, 256, 0, stream>>>(bufB, rowptr, esrc, dis, end_b1, bufA, M);

    gemm_n3_kernel<<<cdiv(M * 64, 256), 256, 0, stream>>>(bufA, end_W2, dis, B3, M);
    spmm3_kernel<<<cdiv(M, 256), 256, 0, stream>>>(B3, rowptr, esrc, dis, end_b2, out, M);
}

// Round 4
// 822.009 us; speedup vs baseline: 2.6684x; 1.0598x over previous
//
#include <hip/hip_runtime.h>
#include <hip/hip_bf16.h>

#define N_FINE 50000
#define N_COARSE 2000
#define N_EDGES 300000

typedef short  s16x8 __attribute__((ext_vector_type(8)));
typedef float  f32x4 __attribute__((ext_vector_type(4)));

static inline int cdiv(int a, int b) { return (a + b - 1) / b; }

__device__ __forceinline__ short f2b(float f) {      // f32 -> bf16 RNE
    unsigned u = __builtin_bit_cast(unsigned, f);
    unsigned r = (u + 0x7fffu + ((u >> 16) & 1u)) >> 16;
    return (short)r;
}
__device__ __forceinline__ float b2f(short s) {
    return __builtin_bit_cast(float, ((unsigned)(unsigned short)s) << 16);
}

#define GL16(gsrc, ldst) __builtin_amdgcn_global_load_lds( \
    (const __attribute__((address_space(1))) unsigned*)(gsrc), \
    (__attribute__((address_space(3))) unsigned*)(ldst), 16, 0, 0)

// ---------------- CSR build ----------------

__global__ void count_edges_kernel(const int* __restrict__ col, int* __restrict__ counts, int ne) {
    int e = blockIdx.x * 256 + threadIdx.x;
    if (e < ne) atomicAdd(&counts[col[e]], 1);
}

__global__ void compute_dis_kernel(const int* __restrict__ counts, float* __restrict__ dis, int n) {
    int i = blockIdx.x * 256 + threadIdx.x;
    if (i < n) dis[i] = rsqrtf((float)(counts[i] + 1));   // +1 self loop
}

// two-level scan: per-block 1024-wide exclusive scan + block totals
__global__ __launch_bounds__(1024) void scan_block_kernel(const int* __restrict__ counts,
        int* __restrict__ rowptr, int* __restrict__ blksum, int n) {
    __shared__ int wsum[16];
    int tid = threadIdx.x, lane = tid & 63, wv = tid >> 6;
    int i = blockIdx.x * 1024 + tid;
    int v = (i < n) ? counts[i] : 0;
    int x = v;
#pragma unroll
    for (int off = 1; off < 64; off <<= 1) {
        int t = __shfl_up(x, off);
        if (lane >= off) x += t;
    }
    if (lane == 63) wsum[wv] = x;
    __syncthreads();
    if (wv == 0) {
        int s = (lane < 16) ? wsum[lane] : 0;
#pragma unroll
        for (int off = 1; off < 16; off <<= 1) {
            int t = __shfl_up(s, off);
            if (lane >= off) s += t;
        }
        if (lane < 16) wsum[lane] = s;
    }
    __syncthreads();
    int prefix = (wv > 0) ? wsum[wv - 1] : 0;
    int incl = prefix + x;
    if (i < n) rowptr[i] = incl - v;   // exclusive
    if (tid == 1023) blksum[blockIdx.x] = incl;
}

__global__ void scan_tops_kernel(int* __restrict__ blksum, int nb) {
    int lane = threadIdx.x;
    int v = (lane < nb) ? blksum[lane] : 0;
    int x = v;
#pragma unroll
    for (int off = 1; off < 64; off <<= 1) {
        int t = __shfl_up(x, off);
        if (lane >= off) x += t;
    }
    if (lane < nb) blksum[lane] = x - v;
}

__global__ void scan_add_kernel(int* __restrict__ rowptr, const int* __restrict__ blksum, int n) {
    int i = blockIdx.x * 256 + threadIdx.x;
    if (i < n) rowptr[i] += blksum[i >> 10];
    else if (i == n) rowptr[n] = N_EDGES;
}

__global__ void scatter_edges_kernel(const int* __restrict__ row, const int* __restrict__ col,
                                     int* __restrict__ cursor, int* __restrict__ esrc, int ne) {
    int e = blockIdx.x * 256 + threadIdx.x;
    if (e < ne) {
        int p = atomicAdd(&cursor[col[e]], 1);
        esrc[p] = row[e];
    }
}

// ---------------- weight prep: WT[n][k] = bf16(W[k][n]), 512x512, LDS-tiled ----------------
// blockIdx.y selects which of 4 weight matrices; 32x32 f32 tile, coalesced both ways.

__global__ __launch_bounds__(256) void wt4_kernel(
        const float* __restrict__ W0, const float* __restrict__ W1,
        const float* __restrict__ W2, const float* __restrict__ W3,
        short* __restrict__ T0, short* __restrict__ T1,
        short* __restrict__ T2, short* __restrict__ T3) {
    __shared__ float tile[32][33];
    const float* W; short* WT;
    switch (blockIdx.y) {
        case 0: W = W0; WT = T0; break;
        case 1: W = W1; WT = T1; break;
        case 2: W = W2; WT = T2; break;
        default: W = W3; WT = T3; break;
    }
    int bx = blockIdx.x & 15;        // k-tile
    int by = blockIdx.x >> 4;        // n-tile
    int tx = threadIdx.x & 31;
    int ty = threadIdx.x >> 5;
#pragma unroll
    for (int i = 0; i < 4; ++i) {
        int k = bx * 32 + ty + i * 8;
        int n = by * 32 + tx;
        tile[ty + i * 8][tx] = W[(size_t)k * 512 + n];   // coalesced load
    }
    __syncthreads();
#pragma unroll
    for (int i = 0; i < 4; ++i) {
        int n = by * 32 + ty + i * 8;
        int k = bx * 32 + tx;
        WT[(size_t)n * 512 + k] = f2b(tile[tx][ty + i * 8]);  // coalesced store
    }
}

// ---------------- layer kernels ----------------

// first layer: [M,6] @ [6,512], scaled by dis, bf16 out
__global__ void pre0_kernel(const float* __restrict__ x, const float* __restrict__ sdf,
                            const float* __restrict__ W, const float* __restrict__ dis,
                            short* __restrict__ B, int M) {
    int idx = blockIdx.x * 256 + threadIdx.x;
    int m = idx >> 9, n = idx & 511;
    if (m >= M) return;
    float a0 = x[m*5+0], a1 = x[m*5+1], a2 = x[m*5+2], a3 = x[m*5+3], a4 = x[m*5+4], a5 = sdf[m];
    float t = a0*W[n] + a1*W[512+n] + a2*W[1024+n] + a3*W[1536+n] + a4*W[2048+n] + a5*W[2560+n];
    B[(size_t)m*512+n] = f2b(dis[m] * t);
}

// MFMA GEMM, 2-phase double-buffered pipeline (T3 minimum recipe):
// stage(next tile) issued BEFORE compute(current); single __syncthreads per K-step
// (its implicit vmcnt(0) drain waits the overlapped loads).
__global__ __launch_bounds__(256) void gemm512_mfma_kernel(
        const short* __restrict__ A, const short* __restrict__ WT,
        const float* __restrict__ dis, short* __restrict__ C, int M,
        const float* __restrict__ A2, const float* __restrict__ W2) {
    __shared__ __attribute__((aligned(16))) short As[2][4096];   // 2 x 8 KB
    __shared__ __attribute__((aligned(16))) short Bs[2][4096];   // 2 x 8 KB
    int tid  = threadIdx.x;
    int lane = tid & 63;
    int w    = tid >> 6;
    int wr   = w >> 1, wc = w & 1;
    int row0 = blockIdx.x * 128;
    int col0 = blockIdx.y * 128;

    int rb0 = 2 * w, rb1 = 2 * w + 1;
    int rIn = lane & 15, kc = lane >> 4;
    int ar0 = row0 + rb0 * 16 + rIn; if (ar0 >= M) ar0 = M - 1;
    int ar1 = row0 + rb1 * 16 + rIn; if (ar1 >= M) ar1 = M - 1;
    const short* aSrc0 = A  + (size_t)ar0 * 512 + kc * 8;
    const short* aSrc1 = A  + (size_t)ar1 * 512 + kc * 8;
    const short* bSrc0 = WT + (size_t)(col0 + rb0 * 16 + rIn) * 512 + kc * 8;
    const short* bSrc1 = WT + (size_t)(col0 + rb1 * 16 + rIn) * 512 + kc * 8;
    int aOff0 = rb0 * 512, aOff1 = rb1 * 512;   // wave-uniform LDS offsets (shorts)

    f32x4 acc[4][4] = {};

    auto stage = [&](int buf, int k0) {
        GL16(aSrc0 + k0, &As[buf][aOff0]);
        GL16(aSrc1 + k0, &As[buf][aOff1]);
        GL16(bSrc0 + k0, &Bs[buf][aOff0]);
        GL16(bSrc1 + k0, &Bs[buf][aOff1]);
    };
    auto compute = [&](int buf) {
        s16x8 av[4], bv[4];
#pragma unroll
        for (int mi = 0; mi < 4; ++mi) av[mi] = *(const s16x8*)&As[buf][(wr * 4 + mi) * 512 + lane * 8];
#pragma unroll
        for (int ni = 0; ni < 4; ++ni) bv[ni] = *(const s16x8*)&Bs[buf][(wc * 4 + ni) * 512 + lane * 8];
#pragma unroll
        for (int mi = 0; mi < 4; ++mi)
#pragma unroll
            for (int ni = 0; ni < 4; ++ni)
                acc[mi][ni] = __builtin_amdgcn_mfma_f32_16x16x32_bf16(av[mi], bv[ni], acc[mi][ni], 0, 0, 0);
    };

    stage(0, 0);
    __syncthreads();
#pragma unroll 1
    for (int tt = 0; tt < 8; ++tt) {
        int kA = tt * 64 + 32;
        if (kA < 512) stage(1, kA);
        compute(0);
        __syncthreads();          // vmcnt(0): buf1 ready; all reads of buf0 done
        int kB = tt * 64 + 64;
        if (kB < 512) stage(0, kB);
        compute(1);
        __syncthreads();          // vmcnt(0): buf0 ready; all reads of buf1 done
    }

    int rbase = row0 + wr * 64;
    int cbase = col0 + wc * 64;
#pragma unroll
    for (int mi = 0; mi < 4; ++mi) {
#pragma unroll
        for (int r = 0; r < 4; ++r) {
            int row = rbase + mi * 16 + (lane >> 4) * 4 + r;
            if (row >= M) continue;
            float d = dis[row];
            float a20 = 0.f, a21 = 0.f, a22 = 0.f;
            if (A2) { a20 = A2[row*3+0]; a21 = A2[row*3+1]; a22 = A2[row*3+2]; }
#pragma unroll
            for (int ni = 0; ni < 4; ++ni) {
                int col = cbase + ni * 16 + (lane & 15);
                float v = acc[mi][ni][r];
                if (A2) v += a20 * W2[col] + a21 * W2[512 + col] + a22 * W2[1024 + col];
                C[(size_t)row * 512 + col] = f2b(d * v);
            }
        }
    }
}

// out[i,:] = bf16(relu( dis[i]*(sum_nbr B[src,:] + B[i,:]) + bias ))  -- one wave/node
__global__ __launch_bounds__(256) void spmm512_kernel(
        const short* __restrict__ B, const int* __restrict__ rowptr, const int* __restrict__ esrc,
        const float* __restrict__ dis, const float* __restrict__ bias,
        short* __restrict__ out, int M) {
    int node = blockIdx.x * 4 + (threadIdx.x >> 6);
    int lane = threadIdx.x & 63;
    if (node >= M) return;
    const s16x8* Bv = (const s16x8*)B;
    s16x8 v = Bv[(size_t)node * 64 + lane];   // self loop
    float acc[8];
#pragma unroll
    for (int j = 0; j < 8; ++j) acc[j] = b2f(v[j]);
    int s = rowptr[node], e = rowptr[node + 1];
    for (int p = s; p < e; ++p) {
        int src = esrc[p];
        s16x8 t = Bv[(size_t)src * 64 + lane];
#pragma unroll
        for (int j = 0; j < 8; ++j) acc[j] += b2f(t[j]);
    }
    float d = dis[node];
    const float4* bp = (const float4*)bias;
    float4 b0 = bp[lane * 2], b1 = bp[lane * 2 + 1];
    float r[8];
    r[0] = d*acc[0] + b0.x; r[1] = d*acc[1] + b0.y; r[2] = d*acc[2] + b0.z; r[3] = d*acc[3] + b0.w;
    r[4] = d*acc[4] + b1.x; r[5] = d*acc[5] + b1.y; r[6] = d*acc[6] + b1.z; r[7] = d*acc[7] + b1.w;
    s16x8 o;
#pragma unroll
    for (int j = 0; j < 8; ++j) o[j] = f2b(fmaxf(r[j], 0.f));
    ((s16x8*)out)[(size_t)node * 64 + lane] = o;
}

// final GEMM: B3[M,3] = dis .* (A_bf16[M,512] @ W[512,3]); one wave per row
__global__ __launch_bounds__(256) void gemm_n3_kernel(
        const short* __restrict__ A, const float* __restrict__ W,
        const float* __restrict__ dis, float* __restrict__ B3, int M) {
    int wid = (blockIdx.x * 256 + threadIdx.x) >> 6;
    int lane = threadIdx.x & 63;
    if (wid >= M) return;
    s16x8 v = ((const s16x8*)A)[(size_t)wid * 64 + lane];
    float s0 = 0.f, s1 = 0.f, s2 = 0.f;
#pragma unroll
    for (int j = 0; j < 8; ++j) {
        float a = b2f(v[j]);
        int k = lane * 8 + j;
        s0 += a * W[k*3+0];
        s1 += a * W[k*3+1];
        s2 += a * W[k*3+2];
    }
    for (int off = 32; off > 0; off >>= 1) {
        s0 += __shfl_down(s0, off);
        s1 += __shfl_down(s1, off);
        s2 += __shfl_down(s2, off);
    }
    if (lane == 0) {
        float d = dis[wid];
        B3[wid*3+0] = d * s0;
        B3[wid*3+1] = d * s1;
        B3[wid*3+2] = d * s2;
    }
}

__global__ void spmm3_kernel(const float* __restrict__ B3, const int* __restrict__ rowptr,
                             const int* __restrict__ esrc, const float* __restrict__ dis,
                             const float* __restrict__ bias, float* __restrict__ out, int M) {
    int i = blockIdx.x * 256 + threadIdx.x;
    if (i >= M) return;
    float a0 = B3[i*3+0], a1 = B3[i*3+1], a2 = B3[i*3+2];
    int s = rowptr[i], e = rowptr[i + 1];
    for (int p = s; p < e; ++p) {
        int src = esrc[p];
        a0 += B3[src*3+0];
        a1 += B3[src*3+1];
        a2 += B3[src*3+2];
    }
    float d = dis[i];
    out[i*3+0] = d * a0 + bias[0];
    out[i*3+1] = d * a1 + bias[1];
    out[i*3+2] = d * a2 + bias[2];
}

// KNN interpolate: block = 64 fine nodes x 4 waves; wave w scans coarse chunk of 500.
__global__ __launch_bounds__(256) void knn_kernel(
        const float* __restrict__ x, const float* __restrict__ cpos,
        const float* __restrict__ cy, float* __restrict__ fy, int M) {
    __shared__ float sd[12][64];
    __shared__ int   si[12][64];
    int lane = threadIdx.x & 63;
    int w = threadIdx.x >> 6;
    int gi = blockIdx.x * 64 + lane;
    int i = (gi < M) ? gi : (M - 1);
    float px = x[i*5+0], py = x[i*5+1];
    float pn2 = px*px + py*py;
    float d0 = 3.0e38f, d1 = 3.0e38f, d2 = 3.0e38f;
    int i0 = 0x7fffffff, i1 = 0x7fffffff, i2 = 0x7fffffff;
    int c0 = w * (N_COARSE / 4), c1 = c0 + (N_COARSE / 4);
    for (int c = c0; c < c1; ++c) {
        float a = cpos[c*2+0], b = cpos[c*2+1];
        float sn2 = a*a + b*b;                       // ref formula
        float d = pn2 + sn2 - 2.f * (px * a + py * b);
        if (d < d2) {
            if (d < d1) {
                d2 = d1; i2 = i1;
                if (d < d0) { d1 = d0; i1 = i0; d0 = d; i0 = c; }
                else       { d1 = d;  i1 = c; }
            } else { d2 = d; i2 = c; }
        }
    }
    sd[w*3+0][lane] = d0; si[w*3+0][lane] = i0;
    sd[w*3+1][lane] = d1; si[w*3+1][lane] = i1;
    sd[w*3+2][lane] = d2; si[w*3+2][lane] = i2;
    __syncthreads();
    if (w != 0 || gi >= M) return;
    float cd[12]; int ci[12];
#pragma unroll
    for (int q = 0; q < 12; ++q) { cd[q] = sd[q][lane]; ci[q] = si[q][lane]; }
    float bd[3]; int bi[3];
#pragma unroll
    for (int s = 0; s < 3; ++s) {
        float best = 3.4e38f; int besti = 0x7fffffff; int bq = 0;
#pragma unroll
        for (int q = 0; q < 12; ++q) {
            bool better = (cd[q] < best) || (cd[q] == best && ci[q] < besti);
            if (better) { best = cd[q]; besti = ci[q]; bq = q; }
        }
        bd[s] = best; bi[s] = besti;
        cd[bq] = 3.4e38f; ci[bq] = 0x7fffffff;
    }
    float w0 = 1.f / fmaxf(bd[0], 1e-16f);
    float w1 = 1.f / fmaxf(bd[1], 1e-16f);
    float w2 = 1.f / fmaxf(bd[2], 1e-16f);
    float ws = w0 + w1 + w2;
    int j0 = bi[0], j1 = bi[1], j2 = bi[2];
#pragma unroll
    for (int j = 0; j < 3; ++j) {
        float v = w0 * cy[j0*3+j] + w1 * cy[j1*3+j] + w2 * cy[j2*3+j];
        fy[gi*3+j] = v / ws;
    }
}

// ---------------- launch ----------------

extern "C" void kernel_launch(void* const* d_in, const int* in_sizes, int n_in,
                              void* d_out, int out_size, void* d_ws, size_t ws_size,
                              hipStream_t stream) {
    const float* x        = (const float*)d_in[0];
    const float* sdf      = (const float*)d_in[1];
    const float* coarse_x = (const float*)d_in[2];
    const float* coarse_y = (const float*)d_in[3];
    const int*   eidx     = (const int*)d_in[4];
    const float* pre_W0   = (const float*)d_in[5];
    const float* pre_b0   = (const float*)d_in[6];
    const float* pre_W1   = (const float*)d_in[7];
    const float* pre_b1   = (const float*)d_in[8];
    const float* pre_W2   = (const float*)d_in[9];
    const float* pre_b2   = (const float*)d_in[10];
    const float* end_W0   = (const float*)d_in[11];
    const float* end_b0   = (const float*)d_in[12];
    const float* end_W1   = (const float*)d_in[13];
    const float* end_b1   = (const float*)d_in[14];
    const float* end_W2   = (const float*)d_in[15];
    const float* end_b2   = (const float*)d_in[16];
    float* out = (float*)d_out;

    const int M = N_FINE, NE = N_EDGES;
    const int* erow = eidx;
    const int* ecol = eidx + NE;

    char* base = (char*)d_ws;
    size_t off = 0;
    auto alloc = [&](size_t bytes) { char* p = base + off; off = (off + bytes + 255) & ~(size_t)255; return p; };
    int*   counts = (int*)  alloc((size_t)M * 4);
    int*   rowptr = (int*)  alloc((size_t)(M + 1) * 4);
    int*   cursor = (int*)  alloc((size_t)M * 4);
    int*   esrc   = (int*)  alloc((size_t)NE * 4);
    int*   blksum = (int*)  alloc((size_t)64 * 4);
    float* dis    = (float*)alloc((size_t)M * 4);
    float* fy     = (float*)alloc((size_t)M * 3 * 4);
    float* B3     = (float*)alloc((size_t)M * 3 * 4);
    short* WT1    = (short*)alloc((size_t)512 * 512 * 2);
    short* WT2    = (short*)alloc((size_t)512 * 512 * 2);
    short* WT3    = (short*)alloc((size_t)512 * 512 * 2);
    short* WT4    = (short*)alloc((size_t)512 * 512 * 2);
    short* bufA   = (short*)alloc((size_t)M * 512 * 2);
    short* bufB   = (short*)alloc((size_t)M * 512 * 2);
    (void)ws_size;

    // weight prep (one launch, 4 matrices)
    wt4_kernel<<<dim3(256, 4), 256, 0, stream>>>(pre_W1, pre_W2, end_W0 + 3 * 512, end_W1,
                                                 WT1, WT2, WT3, WT4);

    // CSR + degrees
    hipMemsetAsync(counts, 0, (size_t)M * 4, stream);
    count_edges_kernel<<<cdiv(NE, 256), 256, 0, stream>>>(ecol, counts, NE);
    compute_dis_kernel<<<cdiv(M, 256), 256, 0, stream>>>(counts, dis, M);
    int nb = cdiv(M, 1024);
    scan_block_kernel<<<nb, 1024, 0, stream>>>(counts, rowptr, blksum, M);
    scan_tops_kernel<<<1, 64, 0, stream>>>(blksum, nb);
    scan_add_kernel<<<cdiv(M + 1, 256), 256, 0, stream>>>(rowptr, blksum, M);
    hipMemcpyAsync(cursor, rowptr, (size_t)M * 4, hipMemcpyDeviceToDevice, stream);
    scatter_edges_kernel<<<cdiv(NE, 256), 256, 0, stream>>>(erow, ecol, cursor, esrc, NE);

    // KNN interpolate
    knn_kernel<<<cdiv(M, 64), 256, 0, stream>>>(x, coarse_x, coarse_y, fy, M);

    dim3 ggrid(cdiv(M, 128), 4);
    int sgrid = cdiv(M, 4);

    pre0_kernel<<<cdiv(M * 512, 256), 256, 0, stream>>>(x, sdf, pre_W0, dis, bufB, M);
    spmm512_kernel<<<sgrid, 256, 0, stream>>>(bufB, rowptr, esrc, dis, pre_b0, bufA, M);

    gemm512_mfma_kernel<<<ggrid, 256, 0, stream>>>(bufA, WT1, dis, bufB, M, nullptr, nullptr);
    spmm512_kernel<<<sgrid, 256, 0, stream>>>(bufB, rowptr, esrc, dis, pre_b1, bufA, M);

    gemm512_mfma_kernel<<<ggrid, 256, 0, stream>>>(bufA, WT2, dis, bufB, M, nullptr, nullptr);
    spmm512_kernel<<<sgrid, 256, 0, stream>>>(bufB, rowptr, esrc, dis, pre_b2, bufA, M);

    gemm512_mfma_kernel<<<ggrid, 256, 0, stream>>>(bufA, WT3, dis, bufB, M, fy, end_W0);
    spmm512_kernel<<<sgrid, 256, 0, stream>>>(bufB, rowptr, esrc, dis, end_b0, bufA, M);

    gemm512_mfma_kernel<<<ggrid, 256, 0, stream>>>(bufA, WT4, dis, bufB, M, nullptr, nullptr);
    spmm512_kernel<<<sgrid, 256, 0, stream>>>(bufB, rowptr, esrc, dis, end_b1, bufA, M);

    gemm_n3_kernel<<<cdiv(M * 64, 256), 256, 0, stream>>>(bufA, end_W2, dis, B3, M);
    spmm3_kernel<<<cdiv(M, 256), 256, 0, stream>>>(B3, rowptr, esrc, dis, end_b2, out, M);
}